// Round 2
// baseline (151.958 us; speedup 1.0000x reference)
//
#include <hip/hip_runtime.h>
#include <math.h>

typedef __attribute__((ext_vector_type(8))) _Float16 f16x8;
typedef __attribute__((ext_vector_type(4))) float f32x4;

#define NPIX 4096
#define C_DIM 128
// 1/sqrt(128) * log2(e): scores arrive in log2-space -> exp2 (v_exp_f32 native)
#define SCALE2 0.12752064638518208f

#if __has_builtin(__builtin_amdgcn_exp2f)
#define EXP2(x) __builtin_amdgcn_exp2f(x)
#else
#define EXP2(x) exp2f(x)
#endif

// ws: fp16 Y panel [b][k][c], rows of 256B, granule-XOR swizzled. 4 MB.
// (The harness poisons the full workspace every iteration regardless of use —
//  measured round 0 vs 1 — so the panel is free; only kernel time matters.)
#define WS_NEED ((size_t)4 << 20)

// ---------------- conv: y fp32 [c][k] -> fp16 panel [k][c], XCD-matched (validated) ----------------
__global__ __launch_bounds__(256) void conv_y(const float* __restrict__ y,
                                              char* __restrict__ ws)
{
    __shared__ float T[32][132];
    const int wg  = blockIdx.x;
    const int xcd = wg & 7;
    const int b   = xcd >> 1;
    const int sl  = ((xcd & 1) << 6) | (wg >> 3);
    const int k0  = sl * 32;
    const int t   = threadIdx.x;

    {   // read 128c x 32k, coalesced
        const int c = t >> 1, half = t & 1;
        const float* srow = y + ((size_t)b * C_DIM + c) * NPIX + k0 + half * 16;
        float4 rv[4];
        #pragma unroll
        for (int u = 0; u < 4; ++u) rv[u] = *(const float4*)(srow + u * 4);
        #pragma unroll
        for (int u = 0; u < 4; ++u) {
            T[half * 16 + u * 4 + 0][c] = rv[u].x;
            T[half * 16 + u * 4 + 1][c] = rv[u].y;
            T[half * 16 + u * 4 + 2][c] = rv[u].z;
            T[half * 16 + u * 4 + 3][c] = rv[u].w;
        }
    }
    __syncthreads();

    char* panel = ws + (size_t)b * (NPIX * 256);
    const int k = t >> 3, g2 = t & 7;
    f16x8 v0, v1;
    #pragma unroll
    for (int m = 0; m < 8; ++m) {
        v0[m] = (_Float16)T[k][g2 * 16 + m];
        v1[m] = (_Float16)T[k][g2 * 16 + 8 + m];
    }
    const int key = k0 + k, s = key & 7;           // granule-XOR swizzle per key row
    char* drow = panel + (size_t)key * 256;
    *(f16x8*)(drow + (((2 * g2)     ^ s) << 4)) = v0;
    *(f16x8*)(drow + (((2 * g2 + 1) ^ s) << 4)) = v1;
}

// ---------------- main: 1024 threads (16 waves = 4/SIMD), register A-frags direct from panel ----------------
// No LDS staging, no in-loop barriers: each wave owns key rows [w*16, w*16+16) of a
// 256-key tile and reads its 4 swizzled f16x8 A-fragments straight from the L2-resident
// panel, register double-buffered one tile ahead. Softmax in log2-space (exp2).
__global__ __launch_bounds__(1024) void uv_main(const char* __restrict__ ws,
                                                const float* __restrict__ x,
                                                float* __restrict__ out)
{
    __shared__ float red[16][64][3];               // cross-wave reduce scratch (12 KB)

    const int t = threadIdx.x, w = t >> 6, l = t & 63;
    const int n16 = l & 15, quad = l >> 4;
    const int wg  = blockIdx.x;
    const int xcd = wg & 7;
    const int b   = xcd >> 1;                      // 2 XCDs per batch: 1MB panel L2-resident
    const int qt  = ((xcd & 1) << 5) | (wg >> 3);  // 0..63
    const int q0  = qt * 64;

    // ---- one-time: X B-fragments fp16 (SCALE2 folded: scores in log2-space). 64 VGPRs. ----
    f16x8 bx[4][4];                                // [cc][qg]
    {
        const float* xq = x + (size_t)b * C_DIM * NPIX + q0 + n16;
        #pragma unroll
        for (int cc = 0; cc < 4; ++cc)
            #pragma unroll
            for (int qg = 0; qg < 4; ++qg) {
                f16x8 hh;
                #pragma unroll
                for (int j = 0; j < 8; ++j)
                    hh[j] = (_Float16)(xq[(size_t)(cc * 32 + quad * 8 + j) * NPIX + qg * 16] * SCALE2);
                bx[cc][qg] = hh;
            }
    }

    // A-frag addresses: row = kt*256 + w*16 + n16; swizzle s = row&7 = n16&7 (w*16 ≡ 0 mod 8)
    const char* panel = ws + (size_t)b * (NPIX * 256);
    const char* yrow  = panel + (size_t)(w * 16 + n16) * 256;
    int goff[4];
    #pragma unroll
    for (int cc = 0; cc < 4; ++cc)
        goff[cc] = ((cc * 4 + quad) ^ (n16 & 7)) << 4;

    // D rows: tile-local key = w*16 + quad*4 + r  (tile = 256 keys)
    float gxv[4];
    #pragma unroll
    for (int r = 0; r < 4; ++r) gxv[r] = (float)((w & 3) * 16 + quad * 4 + r) + 0.5f;
    const float gyw = (float)(w >> 2) + 0.5f;      // gy = 4*kt + gyw
    float den[4] = {0.f, 0.f, 0.f, 0.f}, nu[4] = {0.f, 0.f, 0.f, 0.f}, nv[4] = {0.f, 0.f, 0.f, 0.f};

    f16x8 aA[4], aB[4];

#define LOADA(BUF, KT) do {                                                     \
    const char* rp_ = yrow + (size_t)(KT) * 65536;                              \
    _Pragma("unroll")                                                           \
    for (int cc_ = 0; cc_ < 4; ++cc_)                                           \
        BUF[cc_] = *(const f16x8*)(rp_ + goff[cc_]);                            \
    } while (0)

#define BODY(KT, CUR) do {                                                      \
    f32x4 acc_[4];                                                              \
    _Pragma("unroll")                                                           \
    for (int qg_ = 0; qg_ < 4; ++qg_) acc_[qg_] = (f32x4){0.f, 0.f, 0.f, 0.f};  \
    _Pragma("unroll")                                                           \
    for (int cc_ = 0; cc_ < 4; ++cc_) {                                         \
        _Pragma("unroll")                                                       \
        for (int qg_ = 0; qg_ < 4; ++qg_)                                       \
            acc_[qg_] = __builtin_amdgcn_mfma_f32_16x16x32_f16(CUR[cc_], bx[cc_][qg_], acc_[qg_], 0, 0, 0); \
    }                                                                           \
    const float gy_ = 4.0f * (float)(KT) + gyw;                                 \
    _Pragma("unroll")                                                           \
    for (int qg_ = 0; qg_ < 4; ++qg_) {                                         \
        float ps_ = 0.f, pc_ = 0.f;                                             \
        _Pragma("unroll")                                                       \
        for (int r_ = 0; r_ < 4; ++r_) {                                        \
            const float p_ = EXP2(acc_[qg_][r_]);                               \
            ps_ += p_;                                                          \
            pc_ += p_ * gxv[r_];                                                \
        }                                                                       \
        den[qg_] += ps_;                                                        \
        nu[qg_]  += pc_;                                                        \
        nv[qg_]  += gy_ * ps_;                                                  \
    } } while (0)

    // register double-buffer, one tile of prefetch ahead of the MFMA+softmax body
    LOADA(aA, 0);
    #pragma unroll 1
    for (int kt2 = 0; kt2 < 8; ++kt2) {
        const int kte = 2 * kt2;
        LOADA(aB, kte + 1);
        BODY(kte, aA);
        if (kt2 < 7) LOADA(aA, kte + 2);
        BODY(kte + 1, aB);
    }

#undef LOADA
#undef BODY

    // ---- reduce across quads (keys within wave), then across 16 waves via LDS ----
    #pragma unroll
    for (int qg = 0; qg < 4; ++qg) {
        #pragma unroll
        for (int mk = 16; mk <= 32; mk <<= 1) {
            den[qg] += __shfl_xor(den[qg], mk);
            nu[qg]  += __shfl_xor(nu[qg],  mk);
            nv[qg]  += __shfl_xor(nv[qg],  mk);
        }
    }
    if (quad == 0) {
        #pragma unroll
        for (int qg = 0; qg < 4; ++qg) {
            red[w][qg * 16 + n16][0] = den[qg];
            red[w][qg * 16 + n16][1] = nu[qg];
            red[w][qg * 16 + n16][2] = nv[qg];
        }
    }
    __syncthreads();
    if (t < 64) {
        float d = 0.f, u = 0.f, v = 0.f;
        #pragma unroll
        for (int ww = 0; ww < 16; ++ww) {
            d += red[ww][t][0];
            u += red[ww][t][1];
            v += red[ww][t][2];
        }
        const float inv = 1.0f / d;
        *(float2*)(out + ((size_t)b * NPIX + q0 + t) * 2) =
            make_float2(u * inv * 0.03125f - 1.0f, v * inv * 0.03125f - 1.0f);
    }
}

// ---------------- fallback (fp32 vector kernel, known-correct) if ws too small ----------------
__global__ __launch_bounds__(256, 2) void uv_attn_kernel(
    const float* __restrict__ x, const float* __restrict__ y, float* __restrict__ out)
{
    __shared__ float Xs[C_DIM][32];
    __shared__ float Ysf[64][128];
    const float SCALE = 0.08838834764831845f;
    const int tid = threadIdx.x;
    const int wgid = blockIdx.x;
    const int xcd = wgid & 7;
    const int b = xcd & 3;
    const int q0 = (((xcd >> 2) << 6) | (wgid >> 3)) * 32;
    const float* xb = x + (size_t)b * C_DIM * NPIX + q0;
    {
        const int cr = tid >> 3;
        const int cc = (tid & 7) << 2;
        #pragma unroll
        for (int i = 0; i < 4; ++i) {
            float4 v = *(const float4*)(xb + (size_t)(cr + (i << 5)) * NPIX + cc);
            v.x *= SCALE; v.y *= SCALE; v.z *= SCALE; v.w *= SCALE;
            *(float4*)(&Xs[cr + (i << 5)][cc]) = v;
        }
    }
    const int rg = tid >> 4;
    const int lane16 = tid & 15;
    const int r0 = rg << 1;
    const int col0 = lane16 << 3;
    float gxv[8];
    #pragma unroll
    for (int j2 = 0; j2 < 8; ++j2) gxv[j2] = (float)((col0 & 63) + j2) + 0.5f;
    const float gyb = (float)(lane16 >> 3) + 0.5f;
    float m_run[2] = {-INFINITY, -INFINITY};
    float den[2] = {0.f, 0.f}, nu[2] = {0.f, 0.f}, nv[2] = {0.f, 0.f};
    const int yr = tid >> 5;
    const int yc = (tid & 31) << 2;
    const float* ybase = y + (size_t)b * C_DIM * NPIX;
    for (int kt = 0; kt < 32; ++kt) {
        float S[2][8];
        #pragma unroll
        for (int r = 0; r < 2; ++r)
            #pragma unroll
            for (int j2 = 0; j2 < 8; ++j2) S[r][j2] = 0.f;
        #pragma unroll
        for (int cb = 0; cb < 2; ++cb) {
            __syncthreads();
            const float* yt = ybase + (size_t)(cb << 6) * NPIX + kt * 128;
            #pragma unroll
            for (int i = 0; i < 8; ++i)
                *(float4*)(&Ysf[yr + (i << 3)][yc]) =
                    *(const float4*)(yt + (size_t)(yr + (i << 3)) * NPIX + yc);
            __syncthreads();
            const int cbase = cb << 6;
            #pragma unroll 16
            for (int c = 0; c < 64; ++c) {
                const float2 xa = *(const float2*)(&Xs[cbase + c][r0]);
                const float4 ya = *(const float4*)(&Ysf[c][col0]);
                const float4 yb4 = *(const float4*)(&Ysf[c][col0 + 4]);
                S[0][0] += xa.x * ya.x;  S[0][1] += xa.x * ya.y;
                S[0][2] += xa.x * ya.z;  S[0][3] += xa.x * ya.w;
                S[0][4] += xa.x * yb4.x; S[0][5] += xa.x * yb4.y;
                S[0][6] += xa.x * yb4.z; S[0][7] += xa.x * yb4.w;
                S[1][0] += xa.y * ya.x;  S[1][1] += xa.y * ya.y;
                S[1][2] += xa.y * ya.z;  S[1][3] += xa.y * ya.w;
                S[1][4] += xa.y * yb4.x; S[1][5] += xa.y * yb4.y;
                S[1][6] += xa.y * yb4.z; S[1][7] += xa.y * yb4.w;
            }
        }
        const float gy = gyb + 2.0f * (float)kt;
        #pragma unroll
        for (int r = 0; r < 2; ++r) {
            float tmax = S[r][0];
            #pragma unroll
            for (int j2 = 1; j2 < 8; ++j2) tmax = fmaxf(tmax, S[r][j2]);
            #pragma unroll
            for (int mk = 8; mk >= 1; mk >>= 1) tmax = fmaxf(tmax, __shfl_xor(tmax, mk, 16));
            const float mnew = fmaxf(m_run[r], tmax);
            const float alpha = __expf(m_run[r] - mnew);
            m_run[r] = mnew;
            float psum = 0.f, pu = 0.f;
            #pragma unroll
            for (int j2 = 0; j2 < 8; ++j2) {
                const float p = __expf(S[r][j2] - mnew);
                psum += p; pu += p * gxv[j2];
            }
            den[r] = den[r] * alpha + psum;
            nu[r] = nu[r] * alpha + pu;
            nv[r] = nv[r] * alpha + gy * psum;
        }
    }
    #pragma unroll
    for (int r = 0; r < 2; ++r)
        #pragma unroll
        for (int mk = 8; mk >= 1; mk >>= 1) {
            den[r] += __shfl_xor(den[r], mk, 16);
            nu[r] += __shfl_xor(nu[r], mk, 16);
            nv[r] += __shfl_xor(nv[r], mk, 16);
        }
    if (lane16 == 0) {
        #pragma unroll
        for (int r = 0; r < 2; ++r) {
            const float inv = 1.0f / den[r];
            const int q = q0 + r0 + r;
            *(float2*)(out + ((size_t)b * NPIX + q) * 2) =
                make_float2(nu[r] * inv * 0.03125f - 1.0f, nv[r] * inv * 0.03125f - 1.0f);
        }
    }
}

extern "C" void kernel_launch(void* const* d_in, const int* in_sizes, int n_in,
                              void* d_out, int out_size, void* d_ws, size_t ws_size,
                              hipStream_t stream) {
    const float* x = (const float*)d_in[0];
    const float* y = (const float*)d_in[1];
    float* out = (float*)d_out;
    if (ws_size >= WS_NEED) {
        hipLaunchKernelGGL(conv_y, dim3(512), dim3(256), 0, stream, y, (char*)d_ws);
        hipLaunchKernelGGL(uv_main, dim3(256), dim3(1024), 0, stream,
                           (const char*)d_ws, x, out);
    } else {
        hipLaunchKernelGGL(uv_attn_kernel, dim3(512), dim3(256), 0, stream, x, y, out);
    }
}

// Round 3
// 92.622 us; speedup vs baseline: 1.6406x; 1.6406x over previous
//
#include <hip/hip_runtime.h>
#include <math.h>

typedef __attribute__((ext_vector_type(8))) _Float16 f16x8;
typedef __attribute__((ext_vector_type(4))) float f32x4;

#define NPIX 4096
#define C_DIM 128
// 1/sqrt(128) * log2(e): scores arrive in log2-space -> exp2 (v_exp_f32 native)
#define SCALE2 0.12752064638518208f

#if __has_builtin(__builtin_amdgcn_exp2f)
#define EXP2(x) __builtin_amdgcn_exp2f(x)
#else
#define EXP2(x) exp2f(x)
#endif

// ws: fp16 Y panel [b][k][c], rows of 256B, granule-XOR swizzled. 4 MB.
// (Harness poisons the workspace every iteration regardless of use — measured
//  r0 vs r1 — so the panel is free; only kernel time matters.)
#define WS_NEED ((size_t)4 << 20)

// ---------------- conv: y fp32 [c][k] -> fp16 panel [k][c], XCD-matched (validated) ----------------
__global__ __launch_bounds__(256) void conv_y(const float* __restrict__ y,
                                              char* __restrict__ ws)
{
    __shared__ float T[32][132];
    const int wg  = blockIdx.x;
    const int xcd = wg & 7;
    const int b   = xcd >> 1;
    const int sl  = ((xcd & 1) << 6) | (wg >> 3);
    const int k0  = sl * 32;
    const int t   = threadIdx.x;

    {   // read 128c x 32k, coalesced
        const int c = t >> 1, half = t & 1;
        const float* srow = y + ((size_t)b * C_DIM + c) * NPIX + k0 + half * 16;
        float4 rv[4];
        #pragma unroll
        for (int u = 0; u < 4; ++u) rv[u] = *(const float4*)(srow + u * 4);
        #pragma unroll
        for (int u = 0; u < 4; ++u) {
            T[half * 16 + u * 4 + 0][c] = rv[u].x;
            T[half * 16 + u * 4 + 1][c] = rv[u].y;
            T[half * 16 + u * 4 + 2][c] = rv[u].z;
            T[half * 16 + u * 4 + 3][c] = rv[u].w;
        }
    }
    __syncthreads();

    char* panel = ws + (size_t)b * (NPIX * 256);
    const int k = t >> 3, g2 = t & 7;
    f16x8 v0, v1;
    #pragma unroll
    for (int m = 0; m < 8; ++m) {
        v0[m] = (_Float16)T[k][g2 * 16 + m];
        v1[m] = (_Float16)T[k][g2 * 16 + 8 + m];
    }
    const int key = k0 + k, s = key & 7;           // granule-XOR swizzle per key row
    char* drow = panel + (size_t)key * 256;
    *(f16x8*)(drow + (((2 * g2)     ^ s) << 4)) = v0;
    *(f16x8*)(drow + (((2 * g2 + 1) ^ s) << 4)) = v1;
}

// ---------------- main: 512 blocks x 512 thr (2 blocks/CU -> 4 waves/SIMD), 32 q/block ----------------
// Register footprint sized for the 128-VGPR cap of __launch_bounds__(512,4):
// bx[4][2]=32 + aA/aB=16 + acc=8 + accumulators + addressing ~= 90 VGPRs, no spill
// (r2's failure was a 64-VGPR cap -> 144MB/dispatch scratch traffic).
// A-fragments read directly panel->register (L2-resident), double-buffered one
// 128-key tile ahead; no LDS staging, no in-loop barriers, waves fully decoupled.
__global__ __launch_bounds__(512, 4) void uv_main(const char* __restrict__ ws,
                                                  const float* __restrict__ x,
                                                  float* __restrict__ out)
{
    __shared__ float red[8][32][3];                // cross-wave reduce scratch (3 KB)

    const int t = threadIdx.x, w = t >> 6, l = t & 63;
    const int n16 = l & 15, quad = l >> 4;
    const int wg  = blockIdx.x;
    const int xcd = wg & 7;
    const int b   = xcd >> 1;                      // 2 XCDs per batch: 1MB panel L2-resident
    const int qt  = ((xcd & 1) << 6) | (wg >> 3);  // 0..127
    const int q0  = qt * 32;

    // ---- one-time: X B-fragments fp16 (SCALE2 folded: scores in log2-space). 32 VGPRs. ----
    f16x8 bx[4][2];                                // [cc][qg]
    {
        const float* xq = x + (size_t)b * C_DIM * NPIX + q0 + n16;
        #pragma unroll
        for (int cc = 0; cc < 4; ++cc)
            #pragma unroll
            for (int qg = 0; qg < 2; ++qg) {
                f16x8 hh;
                #pragma unroll
                for (int j = 0; j < 8; ++j)
                    hh[j] = (_Float16)(xq[(size_t)(cc * 32 + quad * 8 + j) * NPIX + qg * 16] * SCALE2);
                bx[cc][qg] = hh;
            }
    }

    // A-frag addresses: row = kt*128 + w*16 + n16; swizzle s = row&7 = n16&7
    const char* panel = ws + (size_t)b * (NPIX * 256);
    const char* yrow  = panel + (size_t)(w * 16 + n16) * 256;
    int goff[4];
    #pragma unroll
    for (int cc = 0; cc < 4; ++cc)
        goff[cc] = ((cc * 4 + quad) ^ (n16 & 7)) << 4;

    // D rows: tile-local key = w*16 + quad*4 + r  (tile = 128 keys = 2 grid rows)
    float gxv[4];
    #pragma unroll
    for (int r = 0; r < 4; ++r) gxv[r] = (float)((w & 3) * 16 + quad * 4 + r) + 0.5f;
    const float gyw = (float)(w >> 2) + 0.5f;      // gy = 2*kt + gyw
    float den[2] = {0.f, 0.f}, nu[2] = {0.f, 0.f}, nv[2] = {0.f, 0.f};

    f16x8 aA[4], aB[4];

#define LOADA(BUF, KT) do {                                                     \
    const char* rp_ = yrow + (size_t)(KT) * 32768;                              \
    _Pragma("unroll")                                                           \
    for (int cc_ = 0; cc_ < 4; ++cc_)                                           \
        BUF[cc_] = *(const f16x8*)(rp_ + goff[cc_]);                            \
    } while (0)

#define BODY(KT, CUR) do {                                                      \
    f32x4 acc_[2];                                                              \
    _Pragma("unroll")                                                           \
    for (int qg_ = 0; qg_ < 2; ++qg_) acc_[qg_] = (f32x4){0.f, 0.f, 0.f, 0.f};  \
    _Pragma("unroll")                                                           \
    for (int cc_ = 0; cc_ < 4; ++cc_) {                                         \
        _Pragma("unroll")                                                       \
        for (int qg_ = 0; qg_ < 2; ++qg_)                                       \
            acc_[qg_] = __builtin_amdgcn_mfma_f32_16x16x32_f16(CUR[cc_], bx[cc_][qg_], acc_[qg_], 0, 0, 0); \
    }                                                                           \
    const float gy_ = 2.0f * (float)(KT) + gyw;                                 \
    _Pragma("unroll")                                                           \
    for (int qg_ = 0; qg_ < 2; ++qg_) {                                         \
        float ps_ = 0.f, pc_ = 0.f;                                             \
        _Pragma("unroll")                                                       \
        for (int r_ = 0; r_ < 4; ++r_) {                                        \
            const float p_ = EXP2(acc_[qg_][r_]);                               \
            ps_ += p_;                                                          \
            pc_ += p_ * gxv[r_];                                                \
        }                                                                       \
        den[qg_] += ps_;                                                        \
        nu[qg_]  += pc_;                                                        \
        nv[qg_]  += gy_ * ps_;                                                  \
    } } while (0)

    // register double-buffer, one tile of prefetch ahead of the MFMA+softmax body
    LOADA(aA, 0);
    #pragma unroll 1
    for (int kt2 = 0; kt2 < 16; ++kt2) {
        const int kte = 2 * kt2;
        LOADA(aB, kte + 1);
        BODY(kte, aA);
        if (kt2 < 15) LOADA(aA, kte + 2);
        BODY(kte + 1, aB);
    }

#undef LOADA
#undef BODY

    // ---- reduce across quads (keys within wave), then across 8 waves via LDS ----
    #pragma unroll
    for (int qg = 0; qg < 2; ++qg) {
        #pragma unroll
        for (int mk = 16; mk <= 32; mk <<= 1) {
            den[qg] += __shfl_xor(den[qg], mk);
            nu[qg]  += __shfl_xor(nu[qg],  mk);
            nv[qg]  += __shfl_xor(nv[qg],  mk);
        }
    }
    if (quad == 0) {
        #pragma unroll
        for (int qg = 0; qg < 2; ++qg) {
            red[w][qg * 16 + n16][0] = den[qg];
            red[w][qg * 16 + n16][1] = nu[qg];
            red[w][qg * 16 + n16][2] = nv[qg];
        }
    }
    __syncthreads();
    if (t < 32) {
        float d = 0.f, u = 0.f, v = 0.f;
        #pragma unroll
        for (int ww = 0; ww < 8; ++ww) {
            d += red[ww][t][0];
            u += red[ww][t][1];
            v += red[ww][t][2];
        }
        const float inv = 1.0f / d;
        *(float2*)(out + ((size_t)b * NPIX + q0 + t) * 2) =
            make_float2(u * inv * 0.03125f - 1.0f, v * inv * 0.03125f - 1.0f);
    }
}

// ---------------- fallback (fp32 vector kernel, known-correct) if ws too small ----------------
__global__ __launch_bounds__(256, 2) void uv_attn_kernel(
    const float* __restrict__ x, const float* __restrict__ y, float* __restrict__ out)
{
    __shared__ float Xs[C_DIM][32];
    __shared__ float Ysf[64][128];
    const float SCALE = 0.08838834764831845f;
    const int tid = threadIdx.x;
    const int wgid = blockIdx.x;
    const int xcd = wgid & 7;
    const int b = xcd & 3;
    const int q0 = (((xcd >> 2) << 6) | (wgid >> 3)) * 32;
    const float* xb = x + (size_t)b * C_DIM * NPIX + q0;
    {
        const int cr = tid >> 3;
        const int cc = (tid & 7) << 2;
        #pragma unroll
        for (int i = 0; i < 4; ++i) {
            float4 v = *(const float4*)(xb + (size_t)(cr + (i << 5)) * NPIX + cc);
            v.x *= SCALE; v.y *= SCALE; v.z *= SCALE; v.w *= SCALE;
            *(float4*)(&Xs[cr + (i << 5)][cc]) = v;
        }
    }
    const int rg = tid >> 4;
    const int lane16 = tid & 15;
    const int r0 = rg << 1;
    const int col0 = lane16 << 3;
    float gxv[8];
    #pragma unroll
    for (int j2 = 0; j2 < 8; ++j2) gxv[j2] = (float)((col0 & 63) + j2) + 0.5f;
    const float gyb = (float)(lane16 >> 3) + 0.5f;
    float m_run[2] = {-INFINITY, -INFINITY};
    float den[2] = {0.f, 0.f}, nu[2] = {0.f, 0.f}, nv[2] = {0.f, 0.f};
    const int yr = tid >> 5;
    const int yc = (tid & 31) << 2;
    const float* ybase = y + (size_t)b * C_DIM * NPIX;
    for (int kt = 0; kt < 32; ++kt) {
        float S[2][8];
        #pragma unroll
        for (int r = 0; r < 2; ++r)
            #pragma unroll
            for (int j2 = 0; j2 < 8; ++j2) S[r][j2] = 0.f;
        #pragma unroll
        for (int cb = 0; cb < 2; ++cb) {
            __syncthreads();
            const float* yt = ybase + (size_t)(cb << 6) * NPIX + kt * 128;
            #pragma unroll
            for (int i = 0; i < 8; ++i)
                *(float4*)(&Ysf[yr + (i << 3)][yc]) =
                    *(const float4*)(yt + (size_t)(yr + (i << 3)) * NPIX + yc);
            __syncthreads();
            const int cbase = cb << 6;
            #pragma unroll 16
            for (int c = 0; c < 64; ++c) {
                const float2 xa = *(const float2*)(&Xs[cbase + c][r0]);
                const float4 ya = *(const float4*)(&Ysf[c][col0]);
                const float4 yb4 = *(const float4*)(&Ysf[c][col0 + 4]);
                S[0][0] += xa.x * ya.x;  S[0][1] += xa.x * ya.y;
                S[0][2] += xa.x * ya.z;  S[0][3] += xa.x * ya.w;
                S[0][4] += xa.x * yb4.x; S[0][5] += xa.x * yb4.y;
                S[0][6] += xa.x * yb4.z; S[0][7] += xa.x * yb4.w;
                S[1][0] += xa.y * ya.x;  S[1][1] += xa.y * ya.y;
                S[1][2] += xa.y * ya.z;  S[1][3] += xa.y * ya.w;
                S[1][4] += xa.y * yb4.x; S[1][5] += xa.y * yb4.y;
                S[1][6] += xa.y * yb4.z; S[1][7] += xa.y * yb4.w;
            }
        }
        const float gy = gyb + 2.0f * (float)kt;
        #pragma unroll
        for (int r = 0; r < 2; ++r) {
            float tmax = S[r][0];
            #pragma unroll
            for (int j2 = 1; j2 < 8; ++j2) tmax = fmaxf(tmax, S[r][j2]);
            #pragma unroll
            for (int mk = 8; mk >= 1; mk >>= 1) tmax = fmaxf(tmax, __shfl_xor(tmax, mk, 16));
            const float mnew = fmaxf(m_run[r], tmax);
            const float alpha = __expf(m_run[r] - mnew);
            m_run[r] = mnew;
            float psum = 0.f, pu = 0.f;
            #pragma unroll
            for (int j2 = 0; j2 < 8; ++j2) {
                const float p = __expf(S[r][j2] - mnew);
                psum += p; pu += p * gxv[j2];
            }
            den[r] = den[r] * alpha + psum;
            nu[r] = nu[r] * alpha + pu;
            nv[r] = nv[r] * alpha + gy * psum;
        }
    }
    #pragma unroll
    for (int r = 0; r < 2; ++r)
        #pragma unroll
        for (int mk = 8; mk >= 1; mk >>= 1) {
            den[r] += __shfl_xor(den[r], mk, 16);
            nu[r] += __shfl_xor(nu[r], mk, 16);
            nv[r] += __shfl_xor(nv[r], mk, 16);
        }
    if (lane16 == 0) {
        #pragma unroll
        for (int r = 0; r < 2; ++r) {
            const float inv = 1.0f / den[r];
            const int q = q0 + r0 + r;
            *(float2*)(out + ((size_t)b * NPIX + q) * 2) =
                make_float2(nu[r] * inv * 0.03125f - 1.0f, nv[r] * inv * 0.03125f - 1.0f);
        }
    }
}

extern "C" void kernel_launch(void* const* d_in, const int* in_sizes, int n_in,
                              void* d_out, int out_size, void* d_ws, size_t ws_size,
                              hipStream_t stream) {
    const float* x = (const float*)d_in[0];
    const float* y = (const float*)d_in[1];
    float* out = (float*)d_out;
    if (ws_size >= WS_NEED) {
        hipLaunchKernelGGL(conv_y, dim3(512), dim3(256), 0, stream, y, (char*)d_ws);
        hipLaunchKernelGGL(uv_main, dim3(512), dim3(512), 0, stream,
                           (const char*)d_ws, x, out);
    } else {
        hipLaunchKernelGGL(uv_attn_kernel, dim3(512), dim3(256), 0, stream, x, y, out);
    }
}